// Round 6
// baseline (116.143 us; speedup 1.0000x reference)
//
#include <hip/hip_runtime.h>
#include <math.h>

// SemiConv2d tropical conv: out = max_{ic,kh,kw} min(x_pad, K). f16-packed.
// R6: kill IEEE canonicalization (R5: VALUBusy 55% = 27us issue vs 8.6us pk
// floor -- LLVM inserts v_pk_max(x,x) canon on every minnum/maxnum operand,
// incl. 36 SGPR K values/ic needing s->v moves). Inline asm v_pk_min/max_f16,
// K via "s" constraint (VOP3P 1-SGPR rule). ic-unroll 4 clusters 36 window
// loads -> 8 latency exposures/wave instead of 32. launch_bounds(192,2) lets
// the scheduler hold the batch in VGPRs. Input data has no NaNs -> raw
// v_pk_min == minnum exactly.
//
// ws layout (u32): xh[n][ic][98][48] pairs (x[2j],x[2j+1]), xs[n][ic][98][49]
// shifted pairs (x[2j-1],x[2j]), k2[ocb][ic][4][9] duplicated f16 pairs.
// -inf baked into h rows 0/97 and w edges -> no edge handling in main loop.

#define HH 96
#define WW 96
#define CIN 32
#define OCN 32
#define XH_ROWS 98
#define XH_W 48
#define XS_W 49
#define XH_SLICE (XH_ROWS * XH_W)
#define XS_SLICE (XH_ROWS * XS_W)
#define XH_TOTAL (8 * 32 * XH_SLICE)
#define XS_TOTAL (8 * 32 * XS_SLICE)
#define K2_TOTAL (8 * 32 * 4 * 9)
#define WS_NEED ((size_t)(XH_TOTAL + XS_TOTAL + K2_TOTAL) * 4)
#define NEGH2 0xFC00FC00u

typedef _Float16 h2 __attribute__((ext_vector_type(2)));

__device__ __forceinline__ uint32_t pkmin_vs(uint32_t x, uint32_t k) {
    uint32_t d;
    asm("v_pk_min_f16 %0, %1, %2" : "=v"(d) : "v"(x), "s"(k));
    return d;
}
__device__ __forceinline__ uint32_t pkmax(uint32_t a, uint32_t b) {
    uint32_t d;
    asm("v_pk_max_f16 %0, %1, %2" : "=v"(d) : "v"(a), "v"(b));
    return d;
}

__global__ __launch_bounds__(256) void setup_x(const float* __restrict__ x,
                                               h2* __restrict__ xh, h2* __restrict__ xs) {
    int idx = blockIdx.x * 256 + threadIdx.x;       // over 8*32*98*49 = 1,229,312
    int j  = idx % XS_W;
    int t  = idx / XS_W;
    int hp = t % XH_ROWS;
    int s  = t / XH_ROWS;                           // n*32+ic
    int h  = hp - 1;
    bool hv = (h >= 0) && (h < HH);
    const float* row = x + ((size_t)s * HH + (hv ? h : 0)) * WW;
    float xl = (hv && j > 0)  ? row[2 * j - 1] : -INFINITY;
    float xm = (hv && j < 48) ? row[2 * j]     : -INFINITY;
    float xr = (hv && j < 48) ? row[2 * j + 1] : -INFINITY;
    xs[idx] = h2{(_Float16)xl, (_Float16)xm};
    if (j < 48)
        xh[(t) * XH_W + j] = h2{(_Float16)xm, (_Float16)xr};
}

__global__ __launch_bounds__(256) void setup_k(const float* __restrict__ kk, h2* __restrict__ k2) {
    int idx = blockIdx.x * 256 + threadIdx.x;       // over 9216
    int tap  = idx % 9;
    int ocin = (idx / 9) % 4;
    int ic   = (idx / 36) % CIN;
    int ocb  = idx / (36 * CIN);
    float v = kk[(((ocb * 4 + ocin) * CIN) + ic) * 9 + tap];
    _Float16 hv = (_Float16)v;
    k2[idx] = h2{hv, hv};
}

__global__ __launch_bounds__(192, 2) void semiconv_f16(const uint32_t* __restrict__ xh,
                                                       const uint32_t* __restrict__ xs,
                                                       const uint32_t* __restrict__ k2,
                                                       float* __restrict__ out) {
    const int tid = threadIdx.x;
    const int jj = tid % 48;          // w-pair 0..47
    const int hr = tid / 48;          // 0..3
    const int b  = blockIdx.x;
    const int hp  = b % 24;           // hp FASTEST -> XCD L2 locality (R4 win)
    const int t   = b / 24;
    const int ocb = t & 7;
    const int n   = t >> 3;
    const int h   = hp * 4 + hr;      // one output row per thread

    const uint32_t* xhp = xh + ((size_t)(n * CIN) * XH_ROWS + h) * XH_W + jj;
    const uint32_t* xsp = xs + ((size_t)(n * CIN) * XH_ROWS + h) * XS_W + jj;
    const uint32_t* kp  = k2 + (size_t)ocb * CIN * 36;

    uint32_t acc[4] = {NEGH2, NEGH2, NEGH2, NEGH2};

    for (int ic0 = 0; ic0 < CIN; ic0 += 4) {
        uint32_t wv[4][9];
#pragma unroll
        for (int u = 0; u < 4; ++u) {
            const uint32_t* xhu = xhp + u * XH_SLICE;
            const uint32_t* xsu = xsp + u * XS_SLICE;
#pragma unroll
            for (int r = 0; r < 3; ++r) {
                wv[u][r * 3 + 0] = xsu[r * XS_W];        // kw=0
                wv[u][r * 3 + 1] = xhu[r * XH_W];        // kw=1
                wv[u][r * 3 + 2] = xsu[r * XS_W + 1];    // kw=2
            }
        }
#pragma unroll
        for (int u = 0; u < 4; ++u) {
            const uint32_t* kq0 = kp + (ic0 + u) * 36;
#pragma unroll
            for (int oc = 0; oc < 4; ++oc) {
                const uint32_t* kq = kq0 + oc * 9;       // uniform -> SGPRs
                uint32_t m0 = pkmin_vs(wv[u][0], kq[0]);
                uint32_t m1 = pkmin_vs(wv[u][1], kq[1]);
                uint32_t m2 = pkmin_vs(wv[u][2], kq[2]);
                uint32_t m3 = pkmin_vs(wv[u][3], kq[3]);
                uint32_t m4 = pkmin_vs(wv[u][4], kq[4]);
                uint32_t m5 = pkmin_vs(wv[u][5], kq[5]);
                uint32_t m6 = pkmin_vs(wv[u][6], kq[6]);
                uint32_t m7 = pkmin_vs(wv[u][7], kq[7]);
                uint32_t m8 = pkmin_vs(wv[u][8], kq[8]);
                uint32_t t01 = pkmax(m0, m1), t23 = pkmax(m2, m3);
                uint32_t t45 = pkmax(m4, m5), t67 = pkmax(m6, m7);
                uint32_t tt  = pkmax(pkmax(t01, t23), pkmax(t45, t67));
                acc[oc] = pkmax(acc[oc], pkmax(tt, m8));
            }
        }
        xhp += 4 * XH_SLICE;
        xsp += 4 * XS_SLICE;
    }

#pragma unroll
    for (int oc = 0; oc < 4; ++oc) {
        h2 a = __builtin_bit_cast(h2, acc[oc]);
        float2 v = make_float2((float)a.x, (float)a.y);
        *(float2*)(out + (((size_t)(n * OCN + ocb * 4 + oc)) * HH + h) * WW + 2 * jj) = v;
    }
}

// ---------- f32 fallback if ws is too small ----------
#define NEGINF (-INFINITY)
__global__ __launch_bounds__(192, 8) void semiconv2d_f32(
    const float* __restrict__ x, const float* __restrict__ kk, float* __restrict__ out)
{
    const int tid = threadIdx.x;
    const int w  = tid % WW;
    const int hr = tid / WW;
    const int b   = blockIdx.x;
    const int ocb = b & 7;
    const int hp  = (b >> 3) % 48;
    const int n   = (b >> 3) / 48;
    const int h   = hp * 2 + hr;
    const int oc0 = ocb * 4;
    float a0[4], a1[4], a2[4];
#pragma unroll
    for (int i = 0; i < 4; ++i) { a0[i] = NEGINF; a1[i] = NEGINF; a2[i] = NEGINF; }
    const bool vm = (h > 0), vp = (h < HH - 1);
    const int hm  = vm ? h - 1 : h;
    const int hpl = vp ? h + 1 : h;
    const int cm  = (w > 0) ? -1 : 0;
    const int cp  = (w < WW - 1) ? 1 : 0;
    const float* rm = x + ((size_t)(n * CIN) * HH + hm)  * WW + w;
    const float* r1 = x + ((size_t)(n * CIN) * HH + h)   * WW + w;
    const float* rp = x + ((size_t)(n * CIN) * HH + hpl) * WW + w;
#pragma unroll 2
    for (int ic = 0; ic < CIN; ++ic) {
        float r00 = vm ? rm[cm] : NEGINF, r01 = vm ? rm[0] : NEGINF, r02 = vm ? rm[cp] : NEGINF;
        float r10 = r1[cm], r11 = r1[0], r12 = r1[cp];
        float r20 = vp ? rp[cm] : NEGINF, r21 = vp ? rp[0] : NEGINF, r22 = vp ? rp[cp] : NEGINF;
#pragma unroll
        for (int oc = 0; oc < 4; ++oc) {
            const float* kq = kk + (size_t)(((oc0 + oc) * CIN + ic)) * 9;
            a0[oc] = fmaxf(fmaxf(a0[oc], fminf(r00, kq[0])), fmaxf(fminf(r10, kq[3]), fminf(r20, kq[6])));
            a1[oc] = fmaxf(fmaxf(a1[oc], fminf(r01, kq[1])), fmaxf(fminf(r11, kq[4]), fminf(r21, kq[7])));
            a2[oc] = fmaxf(fmaxf(a2[oc], fminf(r02, kq[2])), fmaxf(fminf(r12, kq[5]), fminf(r22, kq[8])));
        }
        rm += HH * WW; r1 += HH * WW; rp += HH * WW;
    }
#pragma unroll
    for (int oc = 0; oc < 4; ++oc) {
        float v0 = (w > 0)      ? a0[oc] : NEGINF;
        float v2 = (w < WW - 1) ? a2[oc] : NEGINF;
        out[(((size_t)(n * OCN + oc0 + oc)) * HH + h) * WW + w] = fmaxf(fmaxf(v0, a1[oc]), v2);
    }
}

extern "C" void kernel_launch(void* const* d_in, const int* in_sizes, int n_in,
                              void* d_out, int out_size, void* d_ws, size_t ws_size,
                              hipStream_t stream) {
    const float* x  = (const float*)d_in[0];
    const float* kk = (const float*)d_in[1];
    float* out      = (float*)d_out;
    if (ws_size >= WS_NEED) {
        h2* xh = (h2*)d_ws;
        h2* xs = xh + XH_TOTAL;
        h2* k2 = xs + XS_TOTAL;
        setup_x<<<dim3((8 * 32 * XH_ROWS * XS_W) / 256), dim3(256), 0, stream>>>(x, xh, xs);
        setup_k<<<dim3(K2_TOTAL / 256), dim3(256), 0, stream>>>(kk, k2);
        semiconv_f16<<<dim3(8 * 8 * 24), dim3(192), 0, stream>>>(
            (const uint32_t*)xh, (const uint32_t*)xs, (const uint32_t*)k2, out);
    } else {
        semiconv2d_f32<<<dim3(8 * 48 * 8), dim3(192), 0, stream>>>(x, kk, out);
    }
}

// Round 7
// 102.752 us; speedup vs baseline: 1.1303x; 1.1303x over previous
//
#include <hip/hip_runtime.h>
#include <math.h>

// SemiConv2d tropical conv: out = max_{ic,kh,kw} min(x_pad, K). f16-packed.
// R7: collapse 9 window loads/ic -> 3 dwordx2 loads/ic. ws layout
// xq[n*32+ic][98][48] = 4xf16 (x[2j-1], x[2j], x[2j+1], x[2j+2]) per entry:
//   tap(kw=0) = dword0, tap(kw=2) = dword1, tap(kw=1) = alignbit(d1,d0,16).
// R6 evidence: VALU issue 17us but 66% stall -- 32 L2-latency exposures/wave
// (compiler sinks 9-load batches, VGPR=28). 3 loads/ic (6 w/ unroll-2) fit in
// registers -> 16 exposures, each covered ~3x by co-resident waves.
// Keep: inline-asm v_pk_min/max (no IEEE canon), K via "s" constraint,
// hp-fastest block order (XCD L2 locality), -inf baked edges (no branches).

#define HH 96
#define WW 96
#define CIN 32
#define OCN 32
#define XQ_ROWS 98
#define XQ_W 48
#define XQ_SLICE (XQ_ROWS * XQ_W)              // uint2 units
#define XQ_TOTAL (256 * XQ_SLICE)              // uint2 elements
#define K2_TOTAL (8 * 32 * 4 * 9)              // uint32 elements
#define WS_NEED ((size_t)XQ_TOTAL * 8 + (size_t)K2_TOTAL * 4)
#define NEGH2 0xFC00FC00u

typedef _Float16 h2 __attribute__((ext_vector_type(2)));

__device__ __forceinline__ uint32_t pkmin_vs(uint32_t x, uint32_t k) {
    uint32_t d;
    asm("v_pk_min_f16 %0, %1, %2" : "=v"(d) : "v"(x), "s"(k));
    return d;
}
__device__ __forceinline__ uint32_t pkmax(uint32_t a, uint32_t b) {
    uint32_t d;
    asm("v_pk_max_f16 %0, %1, %2" : "=v"(d) : "v"(a), "v"(b));
    return d;
}

__global__ __launch_bounds__(256) void setup_xq(const float* __restrict__ x,
                                                uint2* __restrict__ xq) {
    int idx = blockIdx.x * 256 + threadIdx.x;   // over 256*98*48 = 1,204,224
    int j  = idx % XQ_W;
    int t  = idx / XQ_W;
    int hp = t % XQ_ROWS;
    int s  = t / XQ_ROWS;                       // n*32+ic
    int h  = hp - 1;
    bool hv = (h >= 0) && (h < HH);
    const float* row = x + ((size_t)s * HH + (hv ? h : 0)) * WW;
    float a = (hv && j > 0)        ? row[2 * j - 1] : -INFINITY;
    float b = hv                   ? row[2 * j]     : -INFINITY;
    float c = hv                   ? row[2 * j + 1] : -INFINITY;
    float d = (hv && j < XQ_W - 1) ? row[2 * j + 2] : -INFINITY;
    h2 p0 = {(_Float16)a, (_Float16)b};
    h2 p1 = {(_Float16)c, (_Float16)d};
    uint2 v;
    v.x = __builtin_bit_cast(uint32_t, p0);
    v.y = __builtin_bit_cast(uint32_t, p1);
    xq[idx] = v;
}

__global__ __launch_bounds__(256) void setup_k(const float* __restrict__ kk,
                                               uint32_t* __restrict__ k2) {
    int idx = blockIdx.x * 256 + threadIdx.x;   // over 9216
    int tap  = idx % 9;
    int ocin = (idx / 9) % 4;
    int ic   = (idx / 36) % CIN;
    int ocb  = idx / (36 * CIN);
    float v = kk[(((ocb * 4 + ocin) * CIN) + ic) * 9 + tap];
    _Float16 hv = (_Float16)v;
    h2 p = {hv, hv};
    k2[idx] = __builtin_bit_cast(uint32_t, p);
}

__global__ __launch_bounds__(192) void semiconv_f16(const uint2* __restrict__ xq,
                                                    const uint32_t* __restrict__ k2,
                                                    float* __restrict__ out) {
    const int tid = threadIdx.x;
    const int jj = tid % 48;          // w-pair 0..47
    const int hr = tid / 48;          // 0..3
    const int b  = blockIdx.x;
    const int hp  = b % 24;           // hp FASTEST -> XCD L2 locality (R4 win)
    const int t   = b / 24;
    const int ocb = t & 7;
    const int n   = t >> 3;
    const int h   = hp * 4 + hr;      // one output row per thread

    // padded row r = x row (h-1+r); output h uses padded rows h, h+1, h+2
    const uint2* p = xq + ((size_t)(n * CIN) * XQ_ROWS + h) * XQ_W + jj;
    const uint32_t* kp = k2 + (size_t)ocb * CIN * 36;

    uint32_t acc[4] = {NEGH2, NEGH2, NEGH2, NEGH2};

    for (int ic0 = 0; ic0 < CIN; ic0 += 2) {
        uint2 q[2][3];
#pragma unroll
        for (int u = 0; u < 2; ++u)
#pragma unroll
            for (int r = 0; r < 3; ++r)
                q[u][r] = p[u * XQ_SLICE + r * XQ_W];

#pragma unroll
        for (int u = 0; u < 2; ++u) {
            uint32_t tap[9];
#pragma unroll
            for (int r = 0; r < 3; ++r) {
                tap[r * 3 + 0] = q[u][r].x;
                tap[r * 3 + 1] = __builtin_amdgcn_alignbit(q[u][r].y, q[u][r].x, 16);
                tap[r * 3 + 2] = q[u][r].y;
            }
            const uint32_t* kq0 = kp + (ic0 + u) * 36;
#pragma unroll
            for (int oc = 0; oc < 4; ++oc) {
                const uint32_t* kq = kq0 + oc * 9;       // uniform -> SGPRs
                uint32_t m0 = pkmin_vs(tap[0], kq[0]);
                uint32_t m1 = pkmin_vs(tap[1], kq[1]);
                uint32_t m2 = pkmin_vs(tap[2], kq[2]);
                uint32_t m3 = pkmin_vs(tap[3], kq[3]);
                uint32_t m4 = pkmin_vs(tap[4], kq[4]);
                uint32_t m5 = pkmin_vs(tap[5], kq[5]);
                uint32_t m6 = pkmin_vs(tap[6], kq[6]);
                uint32_t m7 = pkmin_vs(tap[7], kq[7]);
                uint32_t m8 = pkmin_vs(tap[8], kq[8]);
                uint32_t t01 = pkmax(m0, m1), t23 = pkmax(m2, m3);
                uint32_t t45 = pkmax(m4, m5), t67 = pkmax(m6, m7);
                uint32_t tt  = pkmax(pkmax(t01, t23), pkmax(t45, t67));
                acc[oc] = pkmax(acc[oc], pkmax(tt, m8));
            }
        }
        p += 2 * XQ_SLICE;
    }

#pragma unroll
    for (int oc = 0; oc < 4; ++oc) {
        h2 a = __builtin_bit_cast(h2, acc[oc]);
        float2 v = make_float2((float)a.x, (float)a.y);
        *(float2*)(out + (((size_t)(n * OCN + ocb * 4 + oc)) * HH + h) * WW + 2 * jj) = v;
    }
}

// ---------- f32 fallback if ws is too small ----------
#define NEGINF (-INFINITY)
__global__ __launch_bounds__(192, 8) void semiconv2d_f32(
    const float* __restrict__ x, const float* __restrict__ kk, float* __restrict__ out)
{
    const int tid = threadIdx.x;
    const int w  = tid % WW;
    const int hr = tid / WW;
    const int b   = blockIdx.x;
    const int ocb = b & 7;
    const int hp  = (b >> 3) % 48;
    const int n   = (b >> 3) / 48;
    const int h   = hp * 2 + hr;
    const int oc0 = ocb * 4;
    float a0[4], a1[4], a2[4];
#pragma unroll
    for (int i = 0; i < 4; ++i) { a0[i] = NEGINF; a1[i] = NEGINF; a2[i] = NEGINF; }
    const bool vm = (h > 0), vp = (h < HH - 1);
    const int hm  = vm ? h - 1 : h;
    const int hpl = vp ? h + 1 : h;
    const int cm  = (w > 0) ? -1 : 0;
    const int cp  = (w < WW - 1) ? 1 : 0;
    const float* rm = x + ((size_t)(n * CIN) * HH + hm)  * WW + w;
    const float* r1 = x + ((size_t)(n * CIN) * HH + h)   * WW + w;
    const float* rp = x + ((size_t)(n * CIN) * HH + hpl) * WW + w;
#pragma unroll 2
    for (int ic = 0; ic < CIN; ++ic) {
        float r00 = vm ? rm[cm] : NEGINF, r01 = vm ? rm[0] : NEGINF, r02 = vm ? rm[cp] : NEGINF;
        float r10 = r1[cm], r11 = r1[0], r12 = r1[cp];
        float r20 = vp ? rp[cm] : NEGINF, r21 = vp ? rp[0] : NEGINF, r22 = vp ? rp[cp] : NEGINF;
#pragma unroll
        for (int oc = 0; oc < 4; ++oc) {
            const float* kq = kk + (size_t)(((oc0 + oc) * CIN + ic)) * 9;
            a0[oc] = fmaxf(fmaxf(a0[oc], fminf(r00, kq[0])), fmaxf(fminf(r10, kq[3]), fminf(r20, kq[6])));
            a1[oc] = fmaxf(fmaxf(a1[oc], fminf(r01, kq[1])), fmaxf(fminf(r11, kq[4]), fminf(r21, kq[7])));
            a2[oc] = fmaxf(fmaxf(a2[oc], fminf(r02, kq[2])), fmaxf(fminf(r12, kq[5]), fminf(r22, kq[8])));
        }
        rm += HH * WW; r1 += HH * WW; rp += HH * WW;
    }
#pragma unroll
    for (int oc = 0; oc < 4; ++oc) {
        float v0 = (w > 0)      ? a0[oc] : NEGINF;
        float v2 = (w < WW - 1) ? a2[oc] : NEGINF;
        out[(((size_t)(n * OCN + oc0 + oc)) * HH + h) * WW + w] = fmaxf(fmaxf(v0, a1[oc]), v2);
    }
}

extern "C" void kernel_launch(void* const* d_in, const int* in_sizes, int n_in,
                              void* d_out, int out_size, void* d_ws, size_t ws_size,
                              hipStream_t stream) {
    const float* x  = (const float*)d_in[0];
    const float* kk = (const float*)d_in[1];
    float* out      = (float*)d_out;
    if (ws_size >= WS_NEED) {
        uint2* xq    = (uint2*)d_ws;
        uint32_t* k2 = (uint32_t*)(xq + XQ_TOTAL);
        setup_xq<<<dim3(XQ_TOTAL / 256), dim3(256), 0, stream>>>(x, xq);
        setup_k<<<dim3(K2_TOTAL / 256), dim3(256), 0, stream>>>(kk, k2);
        semiconv_f16<<<dim3(8 * 8 * 24), dim3(192), 0, stream>>>(xq, k2, out);
    } else {
        semiconv2d_f32<<<dim3(8 * 48 * 8), dim3(192), 0, stream>>>(x, kk, out);
    }
}